// Round 4
// baseline (141.512 us; speedup 1.0000x reference)
//
#include <hip/hip_runtime.h>
#include <hip/hip_bf16.h>
#include <math.h>

// Problem constants: N=6, B=2, H=12, T=1024, D=768, scaling = 1/sqrt(64) = 0.125
#define PN 6
#define PB 2
#define PH 12
#define PT 1024
#define PD 768

#define NBLOCKS 2048
#define NTHREADS 256

typedef float f4 __attribute__((ext_vector_type(4)));

// ---------------------------------------------------------------------------
// Kernel 1: per (b,t) row compute e_scaled[n] = 0.125 * exp(a[n]) where
//   a = GELU_exact(RMSNorm(x) @ w1) @ w2 + bias
// 4 rows per 256-thread block (1 wave per row). float4 x/nw loads.
// Tail parallelized across lanes 0..5 (one erf/exp each, shfl broadcast).
// Output layout: e_ws[n * (B*T) + b*T + t].
// ---------------------------------------------------------------------------
__global__ __launch_bounds__(256) void compute_e_kernel(
    const float* __restrict__ x,      // [B*T, D]
    const float* __restrict__ nw,     // [D]
    const float* __restrict__ w1,     // [D, N] row-major
    const float* __restrict__ w2,     // [N, N] row-major
    const float* __restrict__ bias,   // [N]
    float* __restrict__ e_out)        // [N, B*T]
{
    const int wid  = threadIdx.x >> 6;            // wave in block: 0..3
    const int lane = threadIdx.x & 63;
    const int row  = blockIdx.x * 4 + wid;        // 0 .. B*T-1
    const f4* xr4  = (const f4*)(x + (size_t)row * PD);   // 192 f4 per row
    const f4* nw4  = (const f4*)nw;

    f4 xs[3];
    float sumsq = 0.0f;
#pragma unroll
    for (int k = 0; k < 3; ++k) {
        f4 v = xr4[lane + 64 * k];
        xs[k] = v;
        sumsq += v.x * v.x + v.y * v.y + v.z * v.z + v.w * v.w;
    }
#pragma unroll
    for (int off = 32; off; off >>= 1) sumsq += __shfl_xor(sumsq, off, 64);

    const float eps = 1.1920928955078125e-07f;  // float32 machine eps
    const float inv = rsqrtf(sumsq * (1.0f / (float)PD) + eps);

    float p[PN] = {0.f, 0.f, 0.f, 0.f, 0.f, 0.f};
#pragma unroll
    for (int k = 0; k < 3; ++k) {
        const int d0 = 4 * (lane + 64 * k);
        const f4 nv = xs[k] * inv * nw4[lane + 64 * k];
        const float nvc[4] = {nv.x, nv.y, nv.z, nv.w};
#pragma unroll
        for (int c = 0; c < 4; ++c) {
            const int d = d0 + c;
#pragma unroll
            for (int n = 0; n < PN; ++n) p[n] += nvc[c] * w1[d * PN + n];
        }
    }
#pragma unroll
    for (int n = 0; n < PN; ++n) {
#pragma unroll
        for (int off = 32; off; off >>= 1) p[n] += __shfl_xor(p[n], off, 64);
    }

    // lanes 0..5: one exact-GELU each
    float gl = 0.0f;
    if (lane < PN) {
        const float v = p[lane];
        gl = 0.5f * v * (1.0f + erff(v * 0.7071067811865476f));
    }
    // broadcast g and finish: lane j owns output column j
    float g[PN];
#pragma unroll
    for (int n = 0; n < PN; ++n) g[n] = __shfl(gl, n, 64);

    if (lane < PN) {
        const int j = lane;
        float a = bias[j];
#pragma unroll
        for (int n = 0; n < PN; ++n) a += g[n] * w2[n * PN + j];
        e_out[(size_t)j * (PB * PT) + row] = 0.125f * expf(a);
    }
}

// ---------------------------------------------------------------------------
// Kernel 2: out[i] = sum_n qk[n*PLANE + i] * e[n, b(i), t(i)]
// R2 structure (best so far): grid-stride, unroll 2, t4 loop-invariant,
// e-values hoisted. Plain (cached) qk loads this round; nt stores kept.
// 32-bit plane-local offsets for SADDR addressing.
// ---------------------------------------------------------------------------
__global__ __launch_bounds__(NTHREADS) void combine_kernel(
    const float* __restrict__ qk,   // [N, B, H, T, T]
    const float* __restrict__ e,    // [N, B*T]
    float* __restrict__ out)        // [B, H, T, T]
{
    const uint32_t T4       = PT / 4;                        // 256
    const uint32_t PLANE4   = (uint32_t)PB * PH * PT * T4;   // 6,291,456
    const uint32_t BSTRIDE4 = (uint32_t)PH * PT * T4;        // 3,145,728 = 6*stride
    const uint32_t stride   = (uint32_t)NBLOCKS * NTHREADS;  // 524,288

    const f4* q4 = (const f4*)qk;
    const f4* e4 = (const f4*)e;
    f4* o4 = (f4*)out;

    const uint32_t tid = (uint32_t)blockIdx.x * NTHREADS + threadIdx.x;
    const uint32_t t4  = tid & (T4 - 1);   // invariant: stride % 256 == 0

#pragma unroll
    for (uint32_t b = 0; b < PB; ++b) {
        // hoist e-table values for this (b, t4)
        f4 ev[PN];
#pragma unroll
        for (uint32_t n = 0; n < PN; ++n)
            ev[n] = e4[n * (PB * T4) + b * T4 + t4];

        const uint32_t end = (b + 1) * BSTRIDE4;
#pragma unroll 2
        for (uint32_t i4 = b * BSTRIDE4 + tid; i4 < end; i4 += stride) {
            f4 acc = (f4)(0.0f);
#pragma unroll
            for (uint32_t n = 0; n < PN; ++n) {
                const f4 qv = q4[n * PLANE4 + i4];
                acc += qv * ev[n];
            }
            __builtin_nontemporal_store(acc, &o4[i4]);
        }
    }
}

extern "C" void kernel_launch(void* const* d_in, const int* in_sizes, int n_in,
                              void* d_out, int out_size, void* d_ws, size_t ws_size,
                              hipStream_t stream) {
    const float* qk   = (const float*)d_in[0];  // [N,B,H,T,T]
    const float* x    = (const float*)d_in[1];  // [B,T,D]
    const float* nw   = (const float*)d_in[2];  // [D]
    const float* w1   = (const float*)d_in[3];  // [D,N]
    const float* w2   = (const float*)d_in[4];  // [N,N]
    const float* bias = (const float*)d_in[5];  // [N]
    float* out = (float*)d_out;

    float* e_ws = (float*)d_ws;                 // N*B*T floats = 48 KB

    compute_e_kernel<<<(PB * PT) / 4, 256, 0, stream>>>(x, nw, w1, w2, bias, e_ws);
    combine_kernel<<<NBLOCKS, NTHREADS, 0, stream>>>(qk, e_ws, out);
}

// Round 5
// 131.160 us; speedup vs baseline: 1.0789x; 1.0789x over previous
//
#include <hip/hip_runtime.h>
#include <hip/hip_bf16.h>
#include <math.h>

// Problem constants: N=6, B=2, H=12, T=1024, D=768, scaling = 1/sqrt(64) = 0.125
#define PN 6
#define PB 2
#define PH 12
#define PT 1024
#define PD 768

#define NBLOCKS 2048
#define NTHREADS 256

typedef float f4 __attribute__((ext_vector_type(4)));

// ---------------------------------------------------------------------------
// Kernel 1: per (b,t) row compute e_scaled[n] = 0.125 * exp(a[n]) where
//   a = GELU_exact(RMSNorm(x) @ w1) @ w2 + bias
// 4 rows per 256-thread block (1 wave per row). float4 x/nw loads.
// Tail parallelized across lanes 0..5. Output: e_ws[n * (B*T) + b*T + t].
// ---------------------------------------------------------------------------
__global__ __launch_bounds__(256) void compute_e_kernel(
    const float* __restrict__ x,      // [B*T, D]
    const float* __restrict__ nw,     // [D]
    const float* __restrict__ w1,     // [D, N] row-major
    const float* __restrict__ w2,     // [N, N] row-major
    const float* __restrict__ bias,   // [N]
    float* __restrict__ e_out)        // [N, B*T]
{
    const int wid  = threadIdx.x >> 6;            // wave in block: 0..3
    const int lane = threadIdx.x & 63;
    const int row  = blockIdx.x * 4 + wid;        // 0 .. B*T-1
    const f4* xr4  = (const f4*)(x + (size_t)row * PD);   // 192 f4 per row
    const f4* nw4  = (const f4*)nw;

    f4 xs[3];
    float sumsq = 0.0f;
#pragma unroll
    for (int k = 0; k < 3; ++k) {
        f4 v = xr4[lane + 64 * k];
        xs[k] = v;
        sumsq += v.x * v.x + v.y * v.y + v.z * v.z + v.w * v.w;
    }
#pragma unroll
    for (int off = 32; off; off >>= 1) sumsq += __shfl_xor(sumsq, off, 64);

    const float eps = 1.1920928955078125e-07f;  // float32 machine eps
    const float inv = rsqrtf(sumsq * (1.0f / (float)PD) + eps);

    float p[PN] = {0.f, 0.f, 0.f, 0.f, 0.f, 0.f};
#pragma unroll
    for (int k = 0; k < 3; ++k) {
        const int d0 = 4 * (lane + 64 * k);
        const f4 nv = xs[k] * inv * nw4[lane + 64 * k];
        const float nvc[4] = {nv.x, nv.y, nv.z, nv.w};
#pragma unroll
        for (int c = 0; c < 4; ++c) {
            const int d = d0 + c;
#pragma unroll
            for (int n = 0; n < PN; ++n) p[n] += nvc[c] * w1[d * PN + n];
        }
    }
#pragma unroll
    for (int n = 0; n < PN; ++n) {
#pragma unroll
        for (int off = 32; off; off >>= 1) p[n] += __shfl_xor(p[n], off, 64);
    }

    // lanes 0..5: one exact-GELU each
    float gl = 0.0f;
    if (lane < PN) {
        const float v = p[lane];
        gl = 0.5f * v * (1.0f + erff(v * 0.7071067811865476f));
    }
    // broadcast g; lane j owns output column j
    float g[PN];
#pragma unroll
    for (int n = 0; n < PN; ++n) g[n] = __shfl(gl, n, 64);

    if (lane < PN) {
        const int j = lane;
        float a = bias[j];
#pragma unroll
        for (int n = 0; n < PN; ++n) a += g[n] * w2[n * PN + j];
        e_out[(size_t)j * (PB * PT) + row] = 0.125f * expf(a);
    }
}

// ---------------------------------------------------------------------------
// Kernel 2: EXACT R2 structure (best measured: 131.8 us total).
// Grid-stride, unroll 2, t4 loop-invariant, e hoisted, nt loads + nt stores,
// size_t addressing.
// ---------------------------------------------------------------------------
__global__ __launch_bounds__(NTHREADS) void combine_kernel(
    const float* __restrict__ qk,   // [N, B, H, T, T]
    const float* __restrict__ e,    // [N, B*T]
    float* __restrict__ out)        // [B, H, T, T]
{
    const size_t T4       = PT / 4;                      // 256
    const size_t PLANE4   = (size_t)PB * PH * PT * T4;   // 6,291,456
    const size_t BSTRIDE4 = (size_t)PH * PT * T4;        // 3,145,728 = 6*stride
    const size_t stride   = (size_t)NBLOCKS * NTHREADS;  // 524,288

    const f4* q4 = (const f4*)qk;
    const f4* e4 = (const f4*)e;
    f4* o4 = (f4*)out;

    const size_t tid = (size_t)blockIdx.x * NTHREADS + threadIdx.x;
    const size_t t4  = tid & (T4 - 1);   // invariant: stride % 256 == 0

#pragma unroll
    for (int b = 0; b < PB; ++b) {
        // hoist e-table values for this (b, t4)
        f4 ev[PN];
#pragma unroll
        for (int n = 0; n < PN; ++n)
            ev[n] = e4[(size_t)n * (PB * T4) + (size_t)b * T4 + t4];

        const size_t end = (size_t)(b + 1) * BSTRIDE4;
#pragma unroll 2
        for (size_t i4 = (size_t)b * BSTRIDE4 + tid; i4 < end; i4 += stride) {
            f4 acc = (f4)(0.0f);
#pragma unroll
            for (int n = 0; n < PN; ++n) {
                const f4 qv = __builtin_nontemporal_load(&q4[(size_t)n * PLANE4 + i4]);
                acc += qv * ev[n];
            }
            __builtin_nontemporal_store(acc, &o4[i4]);
        }
    }
}

extern "C" void kernel_launch(void* const* d_in, const int* in_sizes, int n_in,
                              void* d_out, int out_size, void* d_ws, size_t ws_size,
                              hipStream_t stream) {
    const float* qk   = (const float*)d_in[0];  // [N,B,H,T,T]
    const float* x    = (const float*)d_in[1];  // [B,T,D]
    const float* nw   = (const float*)d_in[2];  // [D]
    const float* w1   = (const float*)d_in[3];  // [D,N]
    const float* w2   = (const float*)d_in[4];  // [N,N]
    const float* bias = (const float*)d_in[5];  // [N]
    float* out = (float*)d_out;

    float* e_ws = (float*)d_ws;                 // N*B*T floats = 48 KB

    compute_e_kernel<<<(PB * PT) / 4, 256, 0, stream>>>(x, nw, w1, w2, bias, e_ws);
    combine_kernel<<<NBLOCKS, NTHREADS, 0, stream>>>(qk, e_ws, out);
}